// Round 22
// baseline (651.219 us; speedup 1.0000x reference)
//
#include <hip/hip_runtime.h>
#include <hip/hip_bf16.h>

#define HD 2048
#define SEQ 1024
#define NHEAD 32
#define NKVH 8
#define DHEAD 64
#define NEXP 8
#define INTER 2048
#define SCALE 0.125f
#define ALPHA 1.702f
#define LIMIT 7.0f

typedef __attribute__((ext_vector_type(8))) short short8;
typedef __attribute__((ext_vector_type(4))) short short4v;
typedef __attribute__((ext_vector_type(4))) float f32x4;

__device__ __forceinline__ unsigned short f2bf(float f) {
  union { float f; unsigned u; } v; v.f = f;
  unsigned r = v.u + 0x7fffu + ((v.u >> 16) & 1u);
  return (unsigned short)(r >> 16);
}
__device__ __forceinline__ float bf2f(unsigned short h) {
  union { unsigned u; float f; } v; v.u = ((unsigned)h) << 16; return v.f;
}
__device__ __forceinline__ void split2(float f, unsigned short& hi, unsigned short& lo) {
  hi = f2bf(f);
  lo = f2bf(f - bf2f(hi));
}

__device__ __forceinline__ f32x4 mfma32(short8 a, short8 b, f32x4 c) {
  return __builtin_amdgcn_mfma_f32_16x16x32_bf16(a, b, c, 0, 0, 0);
}

// async global->LDS, 16B per lane, dest = base + lane*16 (lane-linear)
__device__ __forceinline__ void gl_lds16(const float* g, float* l) {
  __builtin_amdgcn_global_load_lds(
      (const __attribute__((address_space(1))) unsigned int*)g,
      (__attribute__((address_space(3))) unsigned int*)l, 16, 0, 0);
}

// ---------------- RMSNorm fp32 -> split bf16 (hi/lo) ----------------
__global__ __launch_bounds__(256) void rmsnorm_split_kernel(
    const float* __restrict__ x, const float* __restrict__ gamma,
    unsigned short* __restrict__ oh, unsigned short* __restrict__ ol) {
  int row = blockIdx.x, tid = threadIdx.x;
  const float* xr = x + (size_t)row * HD;
  float v[8];
#pragma unroll
  for (int i = 0; i < 8; ++i) v[i] = xr[tid * 8 + i];
  float ss = 0.f;
#pragma unroll
  for (int i = 0; i < 8; ++i) ss += v[i] * v[i];
#pragma unroll
  for (int off = 32; off; off >>= 1) ss += __shfl_xor(ss, off, 64);
  __shared__ float wss[4];
  if ((tid & 63) == 0) wss[tid >> 6] = ss;
  __syncthreads();
  float rs = rsqrtf((wss[0] + wss[1] + wss[2] + wss[3]) * (1.0f / HD) + 1e-5f);
  short8 vh, vl;
#pragma unroll
  for (int i = 0; i < 8; ++i) {
    float val = v[i] * rs * gamma[tid * 8 + i];
    unsigned short h, lo;
    split2(val, h, lo);
    vh[i] = (short)h;
    vl[i] = (short)lo;
  }
  *(short8*)(oh + (size_t)row * HD + tid * 8) = vh;
  *(short8*)(ol + (size_t)row * HD + tid * 8) = vl;
}

// ---------------- RMSNorm fp32 -> single bf16 (MoE input) ----------------
__global__ __launch_bounds__(256) void rmsnorm_plain_kernel(
    const float* __restrict__ x, const float* __restrict__ gamma,
    unsigned short* __restrict__ out) {
  int row = blockIdx.x, tid = threadIdx.x;
  const float* xr = x + (size_t)row * HD;
  float v[8];
#pragma unroll
  for (int i = 0; i < 8; ++i) v[i] = xr[tid * 8 + i];
  float ss = 0.f;
#pragma unroll
  for (int i = 0; i < 8; ++i) ss += v[i] * v[i];
#pragma unroll
  for (int off = 32; off; off >>= 1) ss += __shfl_xor(ss, off, 64);
  __shared__ float wss[4];
  if ((tid & 63) == 0) wss[tid >> 6] = ss;
  __syncthreads();
  float rs = rsqrtf((wss[0] + wss[1] + wss[2] + wss[3]) * (1.0f / HD) + 1e-5f);
  short8 o;
#pragma unroll
  for (int i = 0; i < 8; ++i) o[i] = (short)f2bf(v[i] * rs * gamma[tid * 8 + i]);
  *(short8*)(out + (size_t)row * HD + tid * 8) = o;
}

// ---------------- Unified GEMM via global_load_lds, swizzled LDS -------------
// 4-wave blocks, BK-chunked. fp32 W tile(s) [NMAT][NR][BK] staged async (each
// gl_lds = 1KB contiguous LDS = 256/BK rows); per-lane global source
// pre-swizzled: lw[m][row][slot16] = W[row][slot16 ^ (row&7)]; read applies
// the same XOR -> bank-spread. Double-buffered, one barrier per chunk.
// fp32->bf16 (split hi/lo if SPLIT) at LDS-read time, bit-identical.
// NS=1 (NR=16) for MoE doubles block count at UNCHANGED weight traffic
// (n-split: each W row still read by exactly one block).
// EPI 0: fused QKV (Q[0,2048) K[2048,2560) V[2560,3072)), split outs, V^T.
// EPI 1: O-proj f32 = acc+bias+resid.
// EPI 3: MoE down, f32 per slot (weights-once).
// EPI 4: FUSED MoE gate+up (NMAT=2), activation in epilogue, gated bf16 out.
template <int MT, int NS, bool SPLIT, int EPI, int BK>
__global__ __launch_bounds__(256) void gemm_gl(
    const unsigned short* __restrict__ Ah, const unsigned short* __restrict__ Al,
    int ldA,
    const float* __restrict__ W0, const float* __restrict__ W1,
    const float* __restrict__ W2,
    const float* __restrict__ b0, const float* __restrict__ b1,
    const float* __restrict__ b2,
    const float* __restrict__ resid,
    const int* __restrict__ counts, const int* __restrict__ arows,
    const int* __restrict__ orows,
    unsigned short* __restrict__ oh0, unsigned short* __restrict__ ol0,
    unsigned short* __restrict__ oh1, unsigned short* __restrict__ ol1,
    unsigned short* __restrict__ oh2, unsigned short* __restrict__ ol2,
    float* __restrict__ f0, unsigned short* __restrict__ gated,
    int M, int Kd) {
  constexpr int NR = NS * 16;
  constexpr int NMAT = (EPI == 4) ? 2 : 1;
  constexpr int RPI = 256 / BK;            // rows per 1KB gl_lds instr
  constexpr int SLOTS = BK / 4;            // 16B slots per row
  constexpr int NI = NMAT * NR / (4 * RPI);  // gl_lds instrs per wave
  __shared__ __align__(16) float lw[2][NMAT][NR][BK];
  int tid = threadIdx.x, l = tid & 63, w = tid >> 6;
  int g = l >> 4, q = l & 15;
  int n0 = blockIdx.x * NR;

  const float* WbM[NMAT];
  const float* bias;
  const float* bias2 = nullptr;
  int nloc = n0, e = 0;
  if constexpr (EPI == 0) {
    if (n0 < NHEAD * DHEAD) {
      WbM[0] = W0; bias = b0;
    } else if (n0 < NHEAD * DHEAD + NKVH * DHEAD) {
      WbM[0] = W1; bias = b1; nloc = n0 - NHEAD * DHEAD;
    } else {
      WbM[0] = W2; bias = b2; nloc = n0 - (NHEAD * DHEAD + NKVH * DHEAD);
    }
  } else if constexpr (EPI == 1) {
    WbM[0] = W0; bias = b0;
  } else if constexpr (EPI == 3) {
    e = blockIdx.z;
    WbM[0] = W0 + (size_t)e * HD * INTER;
    bias = b0 + (size_t)e * HD;
  } else {  // EPI == 4: fused gate+up
    e = blockIdx.z;
    WbM[0] = W0 + (size_t)e * INTER * HD;
    WbM[1] = W1 + (size_t)e * INTER * HD;
    bias = b0 + (size_t)e * INTER;
    bias2 = b1 + (size_t)e * INTER;
  }
  int cnt = (EPI >= 3) ? counts[e] : M;

  // staging: global instr gi = w*NI+j covers mat gi/(NR/RPI), rows
  // (gi%(NR/RPI))*RPI .. +RPI-1; lane -> row +l/SLOTS, LDS slot l%SLOTS;
  // source slot pre-swizzled by row&7 (landing is linear)
  const float* sptr[NI];
  float* sdst0[NI];
  float* sdst1[NI];
#pragma unroll
  for (int j = 0; j < NI; ++j) {
    int gi = w * NI + j;
    int mat = gi / (NR / RPI);
    int rr = (gi % (NR / RPI)) * RPI;
    int r = rr + (l / SLOTS);
    int gs = ((l % SLOTS) ^ (r & 7)) * 4;
    sptr[j] = WbM[mat] + (size_t)(nloc + r) * Kd + gs;
    sdst0[j] = &lw[0][mat][rr][0];
    sdst1[j] = &lw[1][mat][rr][0];
  }
  auto stage = [&](int buf, int kc) {
#pragma unroll
    for (int j = 0; j < NI; ++j)
      gl_lds16(sptr[j] + kc, buf ? sdst1[j] : sdst0[j]);
  };

  int mstart = (EPI <= 1) ? blockIdx.y : 0;
  int mstep = (EPI <= 1) ? gridDim.y : 1;
  constexpr int MG = MT * 64;

  for (int mg = mstart; mg * MG < cnt; mg += mstep) {
    int mb = mg * MG + w * (MT * 16);
    const unsigned short* ap[MT];
    const unsigned short* apl[MT];
#pragma unroll
    for (int mt = 0; mt < MT; ++mt) {
      int mm = min(mb + mt * 16 + q, cnt - 1);
      int ar = (EPI >= 3) ? arows[e * SEQ + mm] : mm;
      ap[mt] = Ah + (size_t)ar * ldA + 8 * g;
      if constexpr (SPLIT) apl[mt] = Al + (size_t)ar * ldA + 8 * g;
    }
    f32x4 acc[NMAT][MT][NS];
#pragma unroll
    for (int m2 = 0; m2 < NMAT; ++m2)
#pragma unroll
      for (int mt = 0; mt < MT; ++mt)
#pragma unroll
        for (int ns = 0; ns < NS; ++ns)
          acc[m2][mt][ns] = (f32x4){0.f, 0.f, 0.f, 0.f};

    stage(0, 0);
    short8 ab[2][MT], abl[2][MT];
#pragma unroll
    for (int mt = 0; mt < MT; ++mt) {
      ab[0][mt] = *(const short8*)(ap[mt]);
      ab[1][mt] = *(const short8*)(ap[mt] + 32);
      if constexpr (SPLIT) {
        abl[0][mt] = *(const short8*)(apl[mt]);
        abl[1][mt] = *(const short8*)(apl[mt] + 32);
      }
    }
    __syncthreads();

    int nc = Kd / BK;
    for (int c = 0; c < nc; ++c) {
      int u = c & 1;
      if (c + 1 < nc) stage(u ^ 1, (c + 1) * BK);
#pragma unroll
      for (int kh = 0; kh < BK / 32; ++kh) {
        short8 acur[MT], acl[MT];
#pragma unroll
        for (int mt = 0; mt < MT; ++mt) {
          acur[mt] = ab[kh & 1][mt];
          if constexpr (SPLIT) acl[mt] = abl[kh & 1][mt];
        }
        int kn = c * BK + kh * 32 + 64;
        if (kn < Kd) {
#pragma unroll
          for (int mt = 0; mt < MT; ++mt) {
            ab[kh & 1][mt] = *(const short8*)(ap[mt] + kn);
            if constexpr (SPLIT) abl[kh & 1][mt] = *(const short8*)(apl[mt] + kn);
          }
        }
        short8 wh[NMAT][NS], wl[NMAT][NS];
#pragma unroll
        for (int m2 = 0; m2 < NMAT; ++m2)
#pragma unroll
          for (int ns = 0; ns < NS; ++ns) {
            int row = ns * 16 + q;
            int r7 = q & 7;
            int i0 = ((kh * 8 + g * 2) ^ r7) * 16;
            int i1 = ((kh * 8 + g * 2 + 1) ^ r7) * 16;
            const char* base = (const char*)&lw[u][m2][row][0];
            float4 v0 = *(const float4*)(base + i0);
            float4 v1 = *(const float4*)(base + i1);
            float vv[8] = {v0.x, v0.y, v0.z, v0.w, v1.x, v1.y, v1.z, v1.w};
#pragma unroll
            for (int jj = 0; jj < 8; ++jj) {
              if constexpr (SPLIT) {
                unsigned short h, lo;
                split2(vv[jj], h, lo);
                wh[m2][ns][jj] = (short)h;
                wl[m2][ns][jj] = (short)lo;
              } else {
                wh[m2][ns][jj] = (short)f2bf(vv[jj]);
              }
            }
          }
#pragma unroll
        for (int m2 = 0; m2 < NMAT; ++m2)
#pragma unroll
          for (int mt = 0; mt < MT; ++mt)
#pragma unroll
            for (int ns = 0; ns < NS; ++ns) {
              acc[m2][mt][ns] = mfma32(acur[mt], wh[m2][ns], acc[m2][mt][ns]);
              if constexpr (SPLIT) {
                acc[m2][mt][ns] = mfma32(acur[mt], wl[m2][ns], acc[m2][mt][ns]);
                acc[m2][mt][ns] = mfma32(acl[mt], wh[m2][ns], acc[m2][mt][ns]);
              }
            }
      }
      __syncthreads();
    }
    // ---------------- epilogue ----------------
#pragma unroll
    for (int ns = 0; ns < NS; ++ns) {
      int ncol = nloc + ns * 16 + q;
      float bs = bias[ncol];
      float bs2 = (EPI == 4) ? bias2[ncol] : 0.f;
#pragma unroll
      for (int mt = 0; mt < MT; ++mt) {
#pragma unroll
        for (int r = 0; r < 4; ++r) {
          int mr = mb + mt * 16 + 4 * g + r;
          float val = acc[0][mt][ns][r] + bs;
          if constexpr (EPI == 0) {
            unsigned short h, lo;
            split2(val, h, lo);
            if (n0 < NHEAD * DHEAD) {
              oh0[(size_t)mr * (NHEAD * DHEAD) + ncol] = h;
              ol0[(size_t)mr * (NHEAD * DHEAD) + ncol] = lo;
            } else if (n0 < NHEAD * DHEAD + NKVH * DHEAD) {
              oh1[(size_t)mr * (NKVH * DHEAD) + ncol] = h;
              ol1[(size_t)mr * (NKVH * DHEAD) + ncol] = lo;
            } else {
              oh2[(size_t)ncol * SEQ + mr] = h;
              ol2[(size_t)ncol * SEQ + mr] = lo;
            }
          } else if constexpr (EPI == 1) {
            f0[(size_t)mr * HD + ncol] = val + resid[(size_t)mr * HD + ncol];
          } else if constexpr (EPI == 3) {
            if (mr < cnt) {
              int slot = orows[e * SEQ + mr];
              f0[(size_t)slot * HD + ncol] = val;
            }
          } else {  // EPI == 4: fused activation
            if (mr < cnt) {
              int slot = orows[e * SEQ + mr];
              float up = acc[1][mt][ns][r] + bs2;
              float gc = fminf(val, LIMIT);
              float uc = fminf(fmaxf(up, -LIMIT), LIMIT);
              float glu = gc / (1.f + __expf(-ALPHA * gc));
              gated[(size_t)slot * INTER + ncol] = f2bf((uc + 1.f) * glu);
            }
          }
        }
      }
    }
  }
}

// ---------------- Flash attention with sink, split precision ----------------
__global__ __launch_bounds__(256) void attn_kernel(
    const unsigned short* __restrict__ Qh, const unsigned short* __restrict__ Ql,
    const unsigned short* __restrict__ Kh, const unsigned short* __restrict__ Kl,
    const unsigned short* __restrict__ Vh, const unsigned short* __restrict__ Vl,
    const float* __restrict__ sinks, unsigned short* __restrict__ outh,
    unsigned short* __restrict__ outl) {
  __shared__ __align__(16) unsigned short pbuf[4][2][16][40];
  int l = threadIdx.x & 63, widx = threadIdx.x >> 6;
  int wid = blockIdx.x * 4 + widx;
  int head = wid >> 6, qt = wid & 63;
  int q0 = qt * 16;
  int g = l >> 4, q = l & 15;
  int kvh = head >> 2;
  size_t qoff = (size_t)(q0 + q) * (NHEAD * DHEAD) + head * DHEAD + 8 * g;
  short8 qh0 = *(const short8*)(Qh + qoff);
  short8 qh1 = *(const short8*)(Qh + qoff + 32);
  short8 ql0 = *(const short8*)(Ql + qoff);
  short8 ql1 = *(const short8*)(Ql + qoff + 32);
  float m = sinks[head];
  float lsum = 1.0f;
  f32x4 o[4] = {{0, 0, 0, 0}, {0, 0, 0, 0}, {0, 0, 0, 0}, {0, 0, 0, 0}};
  int qglob = q0 + q;
  for (int kt = 0; kt <= qt; kt += 2) {
    bool hasB = (kt + 1) <= qt;
    size_t koff = (size_t)(kt * 16 + q) * (NKVH * DHEAD) + kvh * DHEAD + 8 * g;
    f32x4 stA = {0, 0, 0, 0};
    {
      short8 kh0 = *(const short8*)(Kh + koff);
      short8 kh1 = *(const short8*)(Kh + koff + 32);
      short8 kl0 = *(const short8*)(Kl + koff);
      short8 kl1 = *(const short8*)(Kl + koff + 32);
      stA = mfma32(kh0, qh0, stA);
      stA = mfma32(kh0, ql0, stA);
      stA = mfma32(kl0, qh0, stA);
      stA = mfma32(kh1, qh1, stA);
      stA = mfma32(kh1, ql1, stA);
      stA = mfma32(kl1, qh1, stA);
    }
    f32x4 stB = {0, 0, 0, 0};
    if (hasB) {
      size_t koff2 = koff + (size_t)16 * (NKVH * DHEAD);
      short8 kh0 = *(const short8*)(Kh + koff2);
      short8 kh1 = *(const short8*)(Kh + koff2 + 32);
      short8 kl0 = *(const short8*)(Kl + koff2);
      short8 kl1 = *(const short8*)(Kl + koff2 + 32);
      stB = mfma32(kh0, qh0, stB);
      stB = mfma32(kh0, ql0, stB);
      stB = mfma32(kl0, qh0, stB);
      stB = mfma32(kh1, qh1, stB);
      stB = mfma32(kh1, ql1, stB);
      stB = mfma32(kl1, qh1, stB);
    }
    float sA[4], sB[4];
#pragma unroll
    for (int r = 0; r < 4; ++r) {
      int keyA = kt * 16 + 4 * g + r;
      sA[r] = (keyA <= qglob) ? stA[r] * SCALE : -1e30f;
      sB[r] = (hasB && keyA + 16 <= qglob) ? stB[r] * SCALE : -1e30f;
    }
    float mt = fmaxf(fmaxf(fmaxf(sA[0], sA[1]), fmaxf(sA[2], sA[3])),
                     fmaxf(fmaxf(sB[0], sB[1]), fmaxf(sB[2], sB[3])));
    mt = fmaxf(mt, __shfl_xor(mt, 16, 64));
    mt = fmaxf(mt, __shfl_xor(mt, 32, 64));
    float mnew = fmaxf(m, mt);
    float corr = __expf(m - mnew);
    float pA[4], pB[4];
    float rsum = 0.f;
#pragma unroll
    for (int r = 0; r < 4; ++r) {
      pA[r] = __expf(sA[r] - mnew);
      pB[r] = __expf(sB[r] - mnew);
      rsum += pA[r] + pB[r];
    }
    rsum += __shfl_xor(rsum, 16, 64);
    rsum += __shfl_xor(rsum, 32, 64);
    lsum = lsum * corr + rsum;
    m = mnew;
#pragma unroll
    for (int dt = 0; dt < 4; ++dt)
#pragma unroll
      for (int r = 0; r < 4; ++r) o[dt][r] *= corr;
    unsigned short ph[8], pl[8];
#pragma unroll
    for (int r = 0; r < 4; ++r) {
      split2(pA[r], ph[r], pl[r]);
      split2(pB[r], ph[4 + r], pl[4 + r]);
    }
    short4v wAh = {(short)ph[0], (short)ph[1], (short)ph[2], (short)ph[3]};
    short4v wBh = {(short)ph[4], (short)ph[5], (short)ph[6], (short)ph[7]};
    short4v wAl = {(short)pl[0], (short)pl[1], (short)pl[2], (short)pl[3]};
    short4v wBl = {(short)pl[4], (short)pl[5], (short)pl[6], (short)pl[7]};
    *(short4v*)&pbuf[widx][0][q][4 * g] = wAh;
    *(short4v*)&pbuf[widx][0][q][16 + 4 * g] = wBh;
    *(short4v*)&pbuf[widx][1][q][4 * g] = wAl;
    *(short4v*)&pbuf[widx][1][q][16 + 4 * g] = wBl;
    asm volatile("s_waitcnt lgkmcnt(0)" ::: "memory");
    short8 pbh = *(const short8*)&pbuf[widx][0][q][8 * g];
    short8 pbl = *(const short8*)&pbuf[widx][1][q][8 * g];
    size_t vbase = (size_t)(kvh * DHEAD) * SEQ + kt * 16 + 8 * g;
#pragma unroll
    for (int dt = 0; dt < 4; ++dt) {
      size_t voff = vbase + (size_t)(dt * 16 + q) * SEQ;
      short8 vh8 = *(const short8*)(Vh + voff);
      short8 vl8 = *(const short8*)(Vl + voff);
      o[dt] = mfma32(vh8, pbh, o[dt]);
      o[dt] = mfma32(vh8, pbl, o[dt]);
      o[dt] = mfma32(vl8, pbh, o[dt]);
    }
  }
  float inv = 1.0f / lsum;
#pragma unroll
  for (int dt = 0; dt < 4; ++dt)
#pragma unroll
    for (int r = 0; r < 4; ++r) {
      float val = o[dt][r] * inv;
      unsigned short h, lo;
      split2(val, h, lo);
      size_t idx = (size_t)qglob * (NHEAD * DHEAD) + head * DHEAD + dt * 16 + 4 * g + r;
      outh[idx] = h;
      outl[idx] = lo;
    }
}

// ---------------- Router: fp64 norm + logits, top-2, slot/weight lists -------
__global__ __launch_bounds__(64) void router_kernel(
    const float* __restrict__ h, const float* __restrict__ gamma,
    const float* __restrict__ rw, const float* __restrict__ rb,
    float* __restrict__ wsel, int* __restrict__ counts,
    int* __restrict__ lists, int* __restrict__ slotof) {
  int t = blockIdx.x;
  int l = threadIdx.x;
  const float* hr = h + (size_t)t * HD;
  double ss = 0.0;
  for (int i = l; i < HD; i += 64) {
    double x = (double)hr[i];
    ss += x * x;
  }
#pragma unroll
  for (int off = 32; off; off >>= 1) ss += __shfl_xor(ss, off, 64);
  double rs = rsqrt(ss * (1.0 / HD) + 1e-5);
  double acc[NEXP];
#pragma unroll
  for (int e = 0; e < NEXP; ++e) acc[e] = 0.0;
  for (int i = l; i < HD; i += 64) {
    double xh = (double)hr[i] * rs * (double)gamma[i];
#pragma unroll
    for (int e = 0; e < NEXP; ++e) acc[e] += xh * (double)rw[e * HD + i];
  }
#pragma unroll
  for (int e = 0; e < NEXP; ++e)
#pragma unroll
    for (int off = 32; off; off >>= 1) acc[e] += __shfl_xor(acc[e], off, 64);
  if (l == 0) {
    double lg[NEXP];
#pragma unroll
    for (int e = 0; e < NEXP; ++e) lg[e] = acc[e] + (double)rb[e];
    int e0 = 0;
#pragma unroll
    for (int e = 1; e < NEXP; ++e)
      if (lg[e] > lg[e0]) e0 = e;
    int e1 = -1;
#pragma unroll
    for (int e = 0; e < NEXP; ++e)
      if (e != e0 && (e1 < 0 || lg[e] > lg[e1])) e1 = e;
    double d = exp(lg[e1] - lg[e0]);
    float p0 = (float)(1.0 / (1.0 + d)), p1 = (float)(d / (1.0 + d));
    wsel[2 * t] = p0;
    wsel[2 * t + 1] = p1;
    int s0 = atomicAdd(&counts[e0], 1);
    lists[e0 * SEQ + s0] = t;
    slotof[e0 * SEQ + s0] = 2 * t;
    int s1 = atomicAdd(&counts[e1], 1);
    lists[e1 * SEQ + s1] = t;
    slotof[e1 * SEQ + s1] = 2 * t + 1;
  }
}

// ---------------- Final: out = h + w0*down[2t] + w1*down[2t+1] --------------
__global__ __launch_bounds__(256) void reduce_kernel(
    const float* __restrict__ hbuf, const float* __restrict__ scr,
    const float* __restrict__ wsel, float* __restrict__ out) {
  int t = blockIdx.x;
  int c = threadIdx.x * 8;
  float w0 = wsel[2 * t], w1 = wsel[2 * t + 1];
  size_t hb = (size_t)t * HD + c;
  size_t s0 = (size_t)(2 * t) * HD + c;
  size_t s1 = (size_t)(2 * t + 1) * HD + c;
#pragma unroll
  for (int j = 0; j < 2; ++j) {
    float4 hv = *(const float4*)(hbuf + hb + 4 * j);
    float4 a = *(const float4*)(scr + s0 + 4 * j);
    float4 b = *(const float4*)(scr + s1 + 4 * j);
    float4 r;
    r.x = hv.x + w0 * a.x + w1 * b.x;
    r.y = hv.y + w0 * a.y + w1 * b.y;
    r.z = hv.z + w0 * a.z + w1 * b.z;
    r.w = hv.w + w0 * a.w + w1 * b.w;
    *(float4*)(out + hb + 4 * j) = r;
  }
}

extern "C" void kernel_launch(void* const* d_in, const int* in_sizes, int n_in,
                              void* d_out, int out_size, void* d_ws,
                              size_t ws_size, hipStream_t stream) {
  const float* x = (const float*)d_in[0];
  const float* ln1 = (const float*)d_in[2];
  const float* ln2 = (const float*)d_in[3];
  const float* Wq = (const float*)d_in[4];
  const float* bq = (const float*)d_in[5];
  const float* Wk = (const float*)d_in[6];
  const float* bk = (const float*)d_in[7];
  const float* Wv = (const float*)d_in[8];
  const float* bv = (const float*)d_in[9];
  const float* Wo = (const float*)d_in[10];
  const float* bo = (const float*)d_in[11];
  const float* sinks = (const float*)d_in[12];
  const float* rw = (const float*)d_in[13];
  const float* rb = (const float*)d_in[14];
  const float* Wg = (const float*)d_in[15];
  const float* bg = (const float*)d_in[16];
  const float* Wu = (const float*)d_in[17];
  const float* bu = (const float*)d_in[18];
  const float* Wd = (const float*)d_in[19];
  const float* bd = (const float*)d_in[20];
  float* out = (float*)d_out;

  char* ws = (char*)d_ws;
  size_t off = 0;
  auto alloc = [&](size_t bytes) {
    void* p = ws + off;
    off += (bytes + 255) & ~(size_t)255;
    return p;
  };
  unsigned short* xnh = (unsigned short*)alloc((size_t)SEQ * HD * 2);
  unsigned short* xnl = (unsigned short*)alloc((size_t)SEQ * HD * 2);
  unsigned short* qbh = (unsigned short*)alloc((size_t)SEQ * NHEAD * DHEAD * 2);
  unsigned short* qbl = (unsigned short*)alloc((size_t)SEQ * NHEAD * DHEAD * 2);
  unsigned short* kbh = (unsigned short*)alloc((size_t)SEQ * NKVH * DHEAD * 2);
  unsigned short* kbl = (unsigned short*)alloc((size_t)SEQ * NKVH * DHEAD * 2);
  unsigned short* vth = (unsigned short*)alloc((size_t)NKVH * DHEAD * SEQ * 2);
  unsigned short* vtl = (unsigned short*)alloc((size_t)NKVH * DHEAD * SEQ * 2);
  unsigned short* ath = (unsigned short*)alloc((size_t)SEQ * NHEAD * DHEAD * 2);
  unsigned short* atl = (unsigned short*)alloc((size_t)SEQ * NHEAD * DHEAD * 2);
  float* hbuf = (float*)alloc((size_t)SEQ * HD * 4);
  unsigned short* hn = (unsigned short*)alloc((size_t)SEQ * HD * 2);
  float* wsel = (float*)alloc((size_t)SEQ * 2 * 4);
  int* counts = (int*)alloc(NEXP * 4);
  int* lists = (int*)alloc((size_t)NEXP * SEQ * 4);
  int* slotof = (int*)alloc((size_t)NEXP * SEQ * 4);
  unsigned short* gated = (unsigned short*)alloc((size_t)2 * SEQ * INTER * 2);
  float* scr = (float*)alloc((size_t)2 * SEQ * HD * 4);
  (void)ws_size;
  (void)off;

  rmsnorm_split_kernel<<<SEQ, 256, 0, stream>>>(x, ln1, xnh, xnl);
  // fused QKV: 96 n-blocks x 8 m-groups = 768 blocks (MT=2, NS=2, BK=128)
  gemm_gl<2, 2, true, 0, 128><<<dim3(96, 8, 1), 256, 0, stream>>>(
      xnh, xnl, HD, Wq, Wk, Wv, bq, bk, bv, nullptr, nullptr, nullptr, nullptr,
      qbh, qbl, kbh, kbl, vth, vtl, nullptr, nullptr, SEQ, HD);
  attn_kernel<<<NHEAD * 64 / 4, 256, 0, stream>>>(qbh, qbl, kbh, kbl, vth, vtl,
                                                  sinks, ath, atl);
  // O-proj: 64 n-blocks x 8 m-groups = 512 blocks (MT=2, NS=2, BK=128)
  gemm_gl<2, 2, true, 1, 128><<<dim3(64, 8, 1), 256, 0, stream>>>(
      ath, atl, NHEAD * DHEAD, Wo, nullptr, nullptr, bo, nullptr, nullptr, x,
      nullptr, nullptr, nullptr, nullptr, nullptr, nullptr, nullptr, nullptr,
      nullptr, hbuf, nullptr, SEQ, NHEAD * DHEAD);
  rmsnorm_plain_kernel<<<SEQ, 256, 0, stream>>>(hbuf, ln2, hn);
  hipMemsetAsync(counts, 0, NEXP * sizeof(int), stream);
  router_kernel<<<SEQ, 64, 0, stream>>>(hbuf, ln2, rw, rb, wsel, counts, lists,
                                        slotof);
  // FUSED gate+up+activation: NS=1 n-split -> 128 n-blocks x 8 experts =
  // 1024 blocks (4/CU) at UNCHANGED weight traffic (each W row read once)
  gemm_gl<5, 1, false, 4, 128><<<dim3(128, 1, 8), 256, 0, stream>>>(
      hn, nullptr, HD, Wg, Wu, nullptr, bg, bu, nullptr, nullptr, counts, lists,
      slotof, nullptr, nullptr, nullptr, nullptr, nullptr, nullptr, nullptr,
      gated, SEQ, HD);
  // down: NS=1 n-split -> 128 n-blocks x 8 experts = 1024 blocks (4/CU)
  gemm_gl<5, 1, false, 3, 128><<<dim3(128, 1, 8), 256, 0, stream>>>(
      gated, nullptr, INTER, Wd, nullptr, nullptr, bd, nullptr, nullptr,
      nullptr, counts, slotof, slotof, nullptr, nullptr, nullptr, nullptr,
      nullptr, nullptr, scr, nullptr, SEQ, INTER);
  reduce_kernel<<<SEQ, 256, 0, stream>>>(hbuf, scr, wsel, out);
}

// Round 23
// 543.656 us; speedup vs baseline: 1.1979x; 1.1979x over previous
//
#include <hip/hip_runtime.h>
#include <hip/hip_bf16.h>

#define HD 2048
#define SEQ 1024
#define NHEAD 32
#define NKVH 8
#define DHEAD 64
#define NEXP 8
#define INTER 2048
#define SCALE 0.125f
#define ALPHA 1.702f
#define LIMIT 7.0f

typedef __attribute__((ext_vector_type(8))) short short8;
typedef __attribute__((ext_vector_type(4))) short short4v;
typedef __attribute__((ext_vector_type(4))) float f32x4;

__device__ __forceinline__ unsigned short f2bf(float f) {
  union { float f; unsigned u; } v; v.f = f;
  unsigned r = v.u + 0x7fffu + ((v.u >> 16) & 1u);
  return (unsigned short)(r >> 16);
}
__device__ __forceinline__ float bf2f(unsigned short h) {
  union { unsigned u; float f; } v; v.u = ((unsigned)h) << 16; return v.f;
}
__device__ __forceinline__ void split2(float f, unsigned short& hi, unsigned short& lo) {
  hi = f2bf(f);
  lo = f2bf(f - bf2f(hi));
}

__device__ __forceinline__ f32x4 mfma32(short8 a, short8 b, f32x4 c) {
  return __builtin_amdgcn_mfma_f32_16x16x32_bf16(a, b, c, 0, 0, 0);
}

// async global->LDS, 16B per lane, dest = base + lane*16 (lane-linear)
__device__ __forceinline__ void gl_lds16(const float* g, float* l) {
  __builtin_amdgcn_global_load_lds(
      (const __attribute__((address_space(1))) unsigned int*)g,
      (__attribute__((address_space(3))) unsigned int*)l, 16, 0, 0);
}

// ---------------- RMSNorm fp32 -> split bf16 (hi/lo) ----------------
__global__ __launch_bounds__(256) void rmsnorm_split_kernel(
    const float* __restrict__ x, const float* __restrict__ gamma,
    unsigned short* __restrict__ oh, unsigned short* __restrict__ ol) {
  int row = blockIdx.x, tid = threadIdx.x;
  const float* xr = x + (size_t)row * HD;
  float v[8];
#pragma unroll
  for (int i = 0; i < 8; ++i) v[i] = xr[tid * 8 + i];
  float ss = 0.f;
#pragma unroll
  for (int i = 0; i < 8; ++i) ss += v[i] * v[i];
#pragma unroll
  for (int off = 32; off; off >>= 1) ss += __shfl_xor(ss, off, 64);
  __shared__ float wss[4];
  if ((tid & 63) == 0) wss[tid >> 6] = ss;
  __syncthreads();
  float rs = rsqrtf((wss[0] + wss[1] + wss[2] + wss[3]) * (1.0f / HD) + 1e-5f);
  short8 vh, vl;
#pragma unroll
  for (int i = 0; i < 8; ++i) {
    float val = v[i] * rs * gamma[tid * 8 + i];
    unsigned short h, lo;
    split2(val, h, lo);
    vh[i] = (short)h;
    vl[i] = (short)lo;
  }
  *(short8*)(oh + (size_t)row * HD + tid * 8) = vh;
  *(short8*)(ol + (size_t)row * HD + tid * 8) = vl;
}

// ---------------- RMSNorm fp32 -> single bf16 (MoE input) ----------------
__global__ __launch_bounds__(256) void rmsnorm_plain_kernel(
    const float* __restrict__ x, const float* __restrict__ gamma,
    unsigned short* __restrict__ out) {
  int row = blockIdx.x, tid = threadIdx.x;
  const float* xr = x + (size_t)row * HD;
  float v[8];
#pragma unroll
  for (int i = 0; i < 8; ++i) v[i] = xr[tid * 8 + i];
  float ss = 0.f;
#pragma unroll
  for (int i = 0; i < 8; ++i) ss += v[i] * v[i];
#pragma unroll
  for (int off = 32; off; off >>= 1) ss += __shfl_xor(ss, off, 64);
  __shared__ float wss[4];
  if ((tid & 63) == 0) wss[tid >> 6] = ss;
  __syncthreads();
  float rs = rsqrtf((wss[0] + wss[1] + wss[2] + wss[3]) * (1.0f / HD) + 1e-5f);
  short8 o;
#pragma unroll
  for (int i = 0; i < 8; ++i) o[i] = (short)f2bf(v[i] * rs * gamma[tid * 8 + i]);
  *(short8*)(out + (size_t)row * HD + tid * 8) = o;
}

// ---------------- Unified GEMM via global_load_lds, swizzled LDS -------------
// 4-wave blocks, BK-chunked (BK=128 halves barrier count and doubles in-flight
// staged bytes vs BK=64; K enumeration order (c,kh) identical -> bitwise-same
// accumulation). fp32 W tile(s) [NMAT][NR][BK] staged async (each gl_lds =
// 1KB contiguous LDS = 256/BK rows); per-lane global source pre-swizzled:
// lw[m][row][slot16] = W[row][slot16 ^ (row&7)]; read applies the same XOR ->
// bank-spread. Double-buffered, one barrier per chunk. fp32->bf16 (split
// hi/lo if SPLIT) at LDS-read time, bit-identical.
// EPI 0: fused QKV (Q[0,2048) K[2048,2560) V[2560,3072)), split outs, V^T.
// EPI 1: O-proj f32 = acc+bias+resid.
// EPI 3: MoE down, f32 per slot (weights-once).
// EPI 4: FUSED MoE gate+up (NMAT=2), activation in epilogue, gated bf16 out.
template <int MT, int NS, bool SPLIT, int EPI, int BK>
__global__ __launch_bounds__(256) void gemm_gl(
    const unsigned short* __restrict__ Ah, const unsigned short* __restrict__ Al,
    int ldA,
    const float* __restrict__ W0, const float* __restrict__ W1,
    const float* __restrict__ W2,
    const float* __restrict__ b0, const float* __restrict__ b1,
    const float* __restrict__ b2,
    const float* __restrict__ resid,
    const int* __restrict__ counts, const int* __restrict__ arows,
    const int* __restrict__ orows,
    unsigned short* __restrict__ oh0, unsigned short* __restrict__ ol0,
    unsigned short* __restrict__ oh1, unsigned short* __restrict__ ol1,
    unsigned short* __restrict__ oh2, unsigned short* __restrict__ ol2,
    float* __restrict__ f0, unsigned short* __restrict__ gated,
    int M, int Kd) {
  constexpr int NR = NS * 16;
  constexpr int NMAT = (EPI == 4) ? 2 : 1;
  constexpr int RPI = 256 / BK;            // rows per 1KB gl_lds instr
  constexpr int SLOTS = BK / 4;            // 16B slots per row
  constexpr int NI = NMAT * NR / (4 * RPI);  // gl_lds instrs per wave
  __shared__ __align__(16) float lw[2][NMAT][NR][BK];
  int tid = threadIdx.x, l = tid & 63, w = tid >> 6;
  int g = l >> 4, q = l & 15;
  int n0 = blockIdx.x * NR;

  const float* WbM[NMAT];
  const float* bias;
  const float* bias2 = nullptr;
  int nloc = n0, e = 0;
  if constexpr (EPI == 0) {
    if (n0 < NHEAD * DHEAD) {
      WbM[0] = W0; bias = b0;
    } else if (n0 < NHEAD * DHEAD + NKVH * DHEAD) {
      WbM[0] = W1; bias = b1; nloc = n0 - NHEAD * DHEAD;
    } else {
      WbM[0] = W2; bias = b2; nloc = n0 - (NHEAD * DHEAD + NKVH * DHEAD);
    }
  } else if constexpr (EPI == 1) {
    WbM[0] = W0; bias = b0;
  } else if constexpr (EPI == 3) {
    e = blockIdx.z;
    WbM[0] = W0 + (size_t)e * HD * INTER;
    bias = b0 + (size_t)e * HD;
  } else {  // EPI == 4: fused gate+up
    e = blockIdx.z;
    WbM[0] = W0 + (size_t)e * INTER * HD;
    WbM[1] = W1 + (size_t)e * INTER * HD;
    bias = b0 + (size_t)e * INTER;
    bias2 = b1 + (size_t)e * INTER;
  }
  int cnt = (EPI >= 3) ? counts[e] : M;

  // staging: global instr gi = w*NI+j covers mat gi/(NR/RPI), rows
  // (gi%(NR/RPI))*RPI .. +RPI-1; lane -> row +l/SLOTS, LDS slot l%SLOTS;
  // source slot pre-swizzled by row&7 (landing is linear)
  const float* sptr[NI];
  float* sdst0[NI];
  float* sdst1[NI];
#pragma unroll
  for (int j = 0; j < NI; ++j) {
    int gi = w * NI + j;
    int mat = gi / (NR / RPI);
    int rr = (gi % (NR / RPI)) * RPI;
    int r = rr + (l / SLOTS);
    int gs = ((l % SLOTS) ^ (r & 7)) * 4;
    sptr[j] = WbM[mat] + (size_t)(nloc + r) * Kd + gs;
    sdst0[j] = &lw[0][mat][rr][0];
    sdst1[j] = &lw[1][mat][rr][0];
  }
  auto stage = [&](int buf, int kc) {
#pragma unroll
    for (int j = 0; j < NI; ++j)
      gl_lds16(sptr[j] + kc, buf ? sdst1[j] : sdst0[j]);
  };

  int mstart = (EPI <= 1) ? blockIdx.y : 0;
  int mstep = (EPI <= 1) ? gridDim.y : 1;
  constexpr int MG = MT * 64;

  for (int mg = mstart; mg * MG < cnt; mg += mstep) {
    int mb = mg * MG + w * (MT * 16);
    const unsigned short* ap[MT];
    const unsigned short* apl[MT];
#pragma unroll
    for (int mt = 0; mt < MT; ++mt) {
      int mm = min(mb + mt * 16 + q, cnt - 1);
      int ar = (EPI >= 3) ? arows[e * SEQ + mm] : mm;
      ap[mt] = Ah + (size_t)ar * ldA + 8 * g;
      if constexpr (SPLIT) apl[mt] = Al + (size_t)ar * ldA + 8 * g;
    }
    f32x4 acc[NMAT][MT][NS];
#pragma unroll
    for (int m2 = 0; m2 < NMAT; ++m2)
#pragma unroll
      for (int mt = 0; mt < MT; ++mt)
#pragma unroll
        for (int ns = 0; ns < NS; ++ns)
          acc[m2][mt][ns] = (f32x4){0.f, 0.f, 0.f, 0.f};

    stage(0, 0);
    short8 ab[2][MT], abl[2][MT];
#pragma unroll
    for (int mt = 0; mt < MT; ++mt) {
      ab[0][mt] = *(const short8*)(ap[mt]);
      ab[1][mt] = *(const short8*)(ap[mt] + 32);
      if constexpr (SPLIT) {
        abl[0][mt] = *(const short8*)(apl[mt]);
        abl[1][mt] = *(const short8*)(apl[mt] + 32);
      }
    }
    __syncthreads();

    int nc = Kd / BK;
    for (int c = 0; c < nc; ++c) {
      int u = c & 1;
      if (c + 1 < nc) stage(u ^ 1, (c + 1) * BK);
#pragma unroll
      for (int kh = 0; kh < BK / 32; ++kh) {
        short8 acur[MT], acl[MT];
#pragma unroll
        for (int mt = 0; mt < MT; ++mt) {
          acur[mt] = ab[kh & 1][mt];
          if constexpr (SPLIT) acl[mt] = abl[kh & 1][mt];
        }
        int kn = c * BK + kh * 32 + 64;
        if (kn < Kd) {
#pragma unroll
          for (int mt = 0; mt < MT; ++mt) {
            ab[kh & 1][mt] = *(const short8*)(ap[mt] + kn);
            if constexpr (SPLIT) abl[kh & 1][mt] = *(const short8*)(apl[mt] + kn);
          }
        }
        short8 wh[NMAT][NS], wl[NMAT][NS];
#pragma unroll
        for (int m2 = 0; m2 < NMAT; ++m2)
#pragma unroll
          for (int ns = 0; ns < NS; ++ns) {
            int row = ns * 16 + q;
            int r7 = q & 7;
            int i0 = ((kh * 8 + g * 2) ^ r7) * 16;
            int i1 = ((kh * 8 + g * 2 + 1) ^ r7) * 16;
            const char* base = (const char*)&lw[u][m2][row][0];
            float4 v0 = *(const float4*)(base + i0);
            float4 v1 = *(const float4*)(base + i1);
            float vv[8] = {v0.x, v0.y, v0.z, v0.w, v1.x, v1.y, v1.z, v1.w};
#pragma unroll
            for (int jj = 0; jj < 8; ++jj) {
              if constexpr (SPLIT) {
                unsigned short h, lo;
                split2(vv[jj], h, lo);
                wh[m2][ns][jj] = (short)h;
                wl[m2][ns][jj] = (short)lo;
              } else {
                wh[m2][ns][jj] = (short)f2bf(vv[jj]);
              }
            }
          }
#pragma unroll
        for (int m2 = 0; m2 < NMAT; ++m2)
#pragma unroll
          for (int mt = 0; mt < MT; ++mt)
#pragma unroll
            for (int ns = 0; ns < NS; ++ns) {
              acc[m2][mt][ns] = mfma32(acur[mt], wh[m2][ns], acc[m2][mt][ns]);
              if constexpr (SPLIT) {
                acc[m2][mt][ns] = mfma32(acur[mt], wl[m2][ns], acc[m2][mt][ns]);
                acc[m2][mt][ns] = mfma32(acl[mt], wh[m2][ns], acc[m2][mt][ns]);
              }
            }
      }
      __syncthreads();
    }
    // ---------------- epilogue ----------------
#pragma unroll
    for (int ns = 0; ns < NS; ++ns) {
      int ncol = nloc + ns * 16 + q;
      float bs = bias[ncol];
      float bs2 = (EPI == 4) ? bias2[ncol] : 0.f;
#pragma unroll
      for (int mt = 0; mt < MT; ++mt) {
#pragma unroll
        for (int r = 0; r < 4; ++r) {
          int mr = mb + mt * 16 + 4 * g + r;
          float val = acc[0][mt][ns][r] + bs;
          if constexpr (EPI == 0) {
            unsigned short h, lo;
            split2(val, h, lo);
            if (n0 < NHEAD * DHEAD) {
              oh0[(size_t)mr * (NHEAD * DHEAD) + ncol] = h;
              ol0[(size_t)mr * (NHEAD * DHEAD) + ncol] = lo;
            } else if (n0 < NHEAD * DHEAD + NKVH * DHEAD) {
              oh1[(size_t)mr * (NKVH * DHEAD) + ncol] = h;
              ol1[(size_t)mr * (NKVH * DHEAD) + ncol] = lo;
            } else {
              oh2[(size_t)ncol * SEQ + mr] = h;
              ol2[(size_t)ncol * SEQ + mr] = lo;
            }
          } else if constexpr (EPI == 1) {
            f0[(size_t)mr * HD + ncol] = val + resid[(size_t)mr * HD + ncol];
          } else if constexpr (EPI == 3) {
            if (mr < cnt) {
              int slot = orows[e * SEQ + mr];
              f0[(size_t)slot * HD + ncol] = val;
            }
          } else {  // EPI == 4: fused activation
            if (mr < cnt) {
              int slot = orows[e * SEQ + mr];
              float up = acc[1][mt][ns][r] + bs2;
              float gc = fminf(val, LIMIT);
              float uc = fminf(fmaxf(up, -LIMIT), LIMIT);
              float glu = gc / (1.f + __expf(-ALPHA * gc));
              gated[(size_t)slot * INTER + ncol] = f2bf((uc + 1.f) * glu);
            }
          }
        }
      }
    }
  }
}

// ---------------- Flash attention with sink, split precision ----------------
__global__ __launch_bounds__(256) void attn_kernel(
    const unsigned short* __restrict__ Qh, const unsigned short* __restrict__ Ql,
    const unsigned short* __restrict__ Kh, const unsigned short* __restrict__ Kl,
    const unsigned short* __restrict__ Vh, const unsigned short* __restrict__ Vl,
    const float* __restrict__ sinks, unsigned short* __restrict__ outh,
    unsigned short* __restrict__ outl) {
  __shared__ __align__(16) unsigned short pbuf[4][2][16][40];
  int l = threadIdx.x & 63, widx = threadIdx.x >> 6;
  int wid = blockIdx.x * 4 + widx;
  int head = wid >> 6, qt = wid & 63;
  int q0 = qt * 16;
  int g = l >> 4, q = l & 15;
  int kvh = head >> 2;
  size_t qoff = (size_t)(q0 + q) * (NHEAD * DHEAD) + head * DHEAD + 8 * g;
  short8 qh0 = *(const short8*)(Qh + qoff);
  short8 qh1 = *(const short8*)(Qh + qoff + 32);
  short8 ql0 = *(const short8*)(Ql + qoff);
  short8 ql1 = *(const short8*)(Ql + qoff + 32);
  float m = sinks[head];
  float lsum = 1.0f;
  f32x4 o[4] = {{0, 0, 0, 0}, {0, 0, 0, 0}, {0, 0, 0, 0}, {0, 0, 0, 0}};
  int qglob = q0 + q;
  for (int kt = 0; kt <= qt; kt += 2) {
    bool hasB = (kt + 1) <= qt;
    size_t koff = (size_t)(kt * 16 + q) * (NKVH * DHEAD) + kvh * DHEAD + 8 * g;
    f32x4 stA = {0, 0, 0, 0};
    {
      short8 kh0 = *(const short8*)(Kh + koff);
      short8 kh1 = *(const short8*)(Kh + koff + 32);
      short8 kl0 = *(const short8*)(Kl + koff);
      short8 kl1 = *(const short8*)(Kl + koff + 32);
      stA = mfma32(kh0, qh0, stA);
      stA = mfma32(kh0, ql0, stA);
      stA = mfma32(kl0, qh0, stA);
      stA = mfma32(kh1, qh1, stA);
      stA = mfma32(kh1, ql1, stA);
      stA = mfma32(kl1, qh1, stA);
    }
    f32x4 stB = {0, 0, 0, 0};
    if (hasB) {
      size_t koff2 = koff + (size_t)16 * (NKVH * DHEAD);
      short8 kh0 = *(const short8*)(Kh + koff2);
      short8 kh1 = *(const short8*)(Kh + koff2 + 32);
      short8 kl0 = *(const short8*)(Kl + koff2);
      short8 kl1 = *(const short8*)(Kl + koff2 + 32);
      stB = mfma32(kh0, qh0, stB);
      stB = mfma32(kh0, ql0, stB);
      stB = mfma32(kl0, qh0, stB);
      stB = mfma32(kh1, qh1, stB);
      stB = mfma32(kh1, ql1, stB);
      stB = mfma32(kl1, qh1, stB);
    }
    float sA[4], sB[4];
#pragma unroll
    for (int r = 0; r < 4; ++r) {
      int keyA = kt * 16 + 4 * g + r;
      sA[r] = (keyA <= qglob) ? stA[r] * SCALE : -1e30f;
      sB[r] = (hasB && keyA + 16 <= qglob) ? stB[r] * SCALE : -1e30f;
    }
    float mt = fmaxf(fmaxf(fmaxf(sA[0], sA[1]), fmaxf(sA[2], sA[3])),
                     fmaxf(fmaxf(sB[0], sB[1]), fmaxf(sB[2], sB[3])));
    mt = fmaxf(mt, __shfl_xor(mt, 16, 64));
    mt = fmaxf(mt, __shfl_xor(mt, 32, 64));
    float mnew = fmaxf(m, mt);
    float corr = __expf(m - mnew);
    float pA[4], pB[4];
    float rsum = 0.f;
#pragma unroll
    for (int r = 0; r < 4; ++r) {
      pA[r] = __expf(sA[r] - mnew);
      pB[r] = __expf(sB[r] - mnew);
      rsum += pA[r] + pB[r];
    }
    rsum += __shfl_xor(rsum, 16, 64);
    rsum += __shfl_xor(rsum, 32, 64);
    lsum = lsum * corr + rsum;
    m = mnew;
#pragma unroll
    for (int dt = 0; dt < 4; ++dt)
#pragma unroll
      for (int r = 0; r < 4; ++r) o[dt][r] *= corr;
    unsigned short ph[8], pl[8];
#pragma unroll
    for (int r = 0; r < 4; ++r) {
      split2(pA[r], ph[r], pl[r]);
      split2(pB[r], ph[4 + r], pl[4 + r]);
    }
    short4v wAh = {(short)ph[0], (short)ph[1], (short)ph[2], (short)ph[3]};
    short4v wBh = {(short)ph[4], (short)ph[5], (short)ph[6], (short)ph[7]};
    short4v wAl = {(short)pl[0], (short)pl[1], (short)pl[2], (short)pl[3]};
    short4v wBl = {(short)pl[4], (short)pl[5], (short)pl[6], (short)pl[7]};
    *(short4v*)&pbuf[widx][0][q][4 * g] = wAh;
    *(short4v*)&pbuf[widx][0][q][16 + 4 * g] = wBh;
    *(short4v*)&pbuf[widx][1][q][4 * g] = wAl;
    *(short4v*)&pbuf[widx][1][q][16 + 4 * g] = wBl;
    asm volatile("s_waitcnt lgkmcnt(0)" ::: "memory");
    short8 pbh = *(const short8*)&pbuf[widx][0][q][8 * g];
    short8 pbl = *(const short8*)&pbuf[widx][1][q][8 * g];
    size_t vbase = (size_t)(kvh * DHEAD) * SEQ + kt * 16 + 8 * g;
#pragma unroll
    for (int dt = 0; dt < 4; ++dt) {
      size_t voff = vbase + (size_t)(dt * 16 + q) * SEQ;
      short8 vh8 = *(const short8*)(Vh + voff);
      short8 vl8 = *(const short8*)(Vl + voff);
      o[dt] = mfma32(vh8, pbh, o[dt]);
      o[dt] = mfma32(vh8, pbl, o[dt]);
      o[dt] = mfma32(vl8, pbh, o[dt]);
    }
  }
  float inv = 1.0f / lsum;
#pragma unroll
  for (int dt = 0; dt < 4; ++dt)
#pragma unroll
    for (int r = 0; r < 4; ++r) {
      float val = o[dt][r] * inv;
      unsigned short h, lo;
      split2(val, h, lo);
      size_t idx = (size_t)qglob * (NHEAD * DHEAD) + head * DHEAD + dt * 16 + 4 * g + r;
      outh[idx] = h;
      outl[idx] = lo;
    }
}

// ---------------- Router: fp64 norm + logits, top-2, slot/weight lists -------
__global__ __launch_bounds__(64) void router_kernel(
    const float* __restrict__ h, const float* __restrict__ gamma,
    const float* __restrict__ rw, const float* __restrict__ rb,
    float* __restrict__ wsel, int* __restrict__ counts,
    int* __restrict__ lists, int* __restrict__ slotof) {
  int t = blockIdx.x;
  int l = threadIdx.x;
  const float* hr = h + (size_t)t * HD;
  double ss = 0.0;
  for (int i = l; i < HD; i += 64) {
    double x = (double)hr[i];
    ss += x * x;
  }
#pragma unroll
  for (int off = 32; off; off >>= 1) ss += __shfl_xor(ss, off, 64);
  double rs = rsqrt(ss * (1.0 / HD) + 1e-5);
  double acc[NEXP];
#pragma unroll
  for (int e = 0; e < NEXP; ++e) acc[e] = 0.0;
  for (int i = l; i < HD; i += 64) {
    double xh = (double)hr[i] * rs * (double)gamma[i];
#pragma unroll
    for (int e = 0; e < NEXP; ++e) acc[e] += xh * (double)rw[e * HD + i];
  }
#pragma unroll
  for (int e = 0; e < NEXP; ++e)
#pragma unroll
    for (int off = 32; off; off >>= 1) acc[e] += __shfl_xor(acc[e], off, 64);
  if (l == 0) {
    double lg[NEXP];
#pragma unroll
    for (int e = 0; e < NEXP; ++e) lg[e] = acc[e] + (double)rb[e];
    int e0 = 0;
#pragma unroll
    for (int e = 1; e < NEXP; ++e)
      if (lg[e] > lg[e0]) e0 = e;
    int e1 = -1;
#pragma unroll
    for (int e = 0; e < NEXP; ++e)
      if (e != e0 && (e1 < 0 || lg[e] > lg[e1])) e1 = e;
    double d = exp(lg[e1] - lg[e0]);
    float p0 = (float)(1.0 / (1.0 + d)), p1 = (float)(d / (1.0 + d));
    wsel[2 * t] = p0;
    wsel[2 * t + 1] = p1;
    int s0 = atomicAdd(&counts[e0], 1);
    lists[e0 * SEQ + s0] = t;
    slotof[e0 * SEQ + s0] = 2 * t;
    int s1 = atomicAdd(&counts[e1], 1);
    lists[e1 * SEQ + s1] = t;
    slotof[e1 * SEQ + s1] = 2 * t + 1;
  }
}

// ---------------- Final: out = h + w0*down[2t] + w1*down[2t+1] --------------
__global__ __launch_bounds__(256) void reduce_kernel(
    const float* __restrict__ hbuf, const float* __restrict__ scr,
    const float* __restrict__ wsel, float* __restrict__ out) {
  int t = blockIdx.x;
  int c = threadIdx.x * 8;
  float w0 = wsel[2 * t], w1 = wsel[2 * t + 1];
  size_t hb = (size_t)t * HD + c;
  size_t s0 = (size_t)(2 * t) * HD + c;
  size_t s1 = (size_t)(2 * t + 1) * HD + c;
#pragma unroll
  for (int j = 0; j < 2; ++j) {
    float4 hv = *(const float4*)(hbuf + hb + 4 * j);
    float4 a = *(const float4*)(scr + s0 + 4 * j);
    float4 b = *(const float4*)(scr + s1 + 4 * j);
    float4 r;
    r.x = hv.x + w0 * a.x + w1 * b.x;
    r.y = hv.y + w0 * a.y + w1 * b.y;
    r.z = hv.z + w0 * a.z + w1 * b.z;
    r.w = hv.w + w0 * a.w + w1 * b.w;
    *(float4*)(out + hb + 4 * j) = r;
  }
}

extern "C" void kernel_launch(void* const* d_in, const int* in_sizes, int n_in,
                              void* d_out, int out_size, void* d_ws,
                              size_t ws_size, hipStream_t stream) {
  const float* x = (const float*)d_in[0];
  const float* ln1 = (const float*)d_in[2];
  const float* ln2 = (const float*)d_in[3];
  const float* Wq = (const float*)d_in[4];
  const float* bq = (const float*)d_in[5];
  const float* Wk = (const float*)d_in[6];
  const float* bk = (const float*)d_in[7];
  const float* Wv = (const float*)d_in[8];
  const float* bv = (const float*)d_in[9];
  const float* Wo = (const float*)d_in[10];
  const float* bo = (const float*)d_in[11];
  const float* sinks = (const float*)d_in[12];
  const float* rw = (const float*)d_in[13];
  const float* rb = (const float*)d_in[14];
  const float* Wg = (const float*)d_in[15];
  const float* bg = (const float*)d_in[16];
  const float* Wu = (const float*)d_in[17];
  const float* bu = (const float*)d_in[18];
  const float* Wd = (const float*)d_in[19];
  const float* bd = (const float*)d_in[20];
  float* out = (float*)d_out;

  char* ws = (char*)d_ws;
  size_t off = 0;
  auto alloc = [&](size_t bytes) {
    void* p = ws + off;
    off += (bytes + 255) & ~(size_t)255;
    return p;
  };
  unsigned short* xnh = (unsigned short*)alloc((size_t)SEQ * HD * 2);
  unsigned short* xnl = (unsigned short*)alloc((size_t)SEQ * HD * 2);
  unsigned short* qbh = (unsigned short*)alloc((size_t)SEQ * NHEAD * DHEAD * 2);
  unsigned short* qbl = (unsigned short*)alloc((size_t)SEQ * NHEAD * DHEAD * 2);
  unsigned short* kbh = (unsigned short*)alloc((size_t)SEQ * NKVH * DHEAD * 2);
  unsigned short* kbl = (unsigned short*)alloc((size_t)SEQ * NKVH * DHEAD * 2);
  unsigned short* vth = (unsigned short*)alloc((size_t)NKVH * DHEAD * SEQ * 2);
  unsigned short* vtl = (unsigned short*)alloc((size_t)NKVH * DHEAD * SEQ * 2);
  unsigned short* ath = (unsigned short*)alloc((size_t)SEQ * NHEAD * DHEAD * 2);
  unsigned short* atl = (unsigned short*)alloc((size_t)SEQ * NHEAD * DHEAD * 2);
  float* hbuf = (float*)alloc((size_t)SEQ * HD * 4);
  unsigned short* hn = (unsigned short*)alloc((size_t)SEQ * HD * 2);
  float* wsel = (float*)alloc((size_t)SEQ * 2 * 4);
  int* counts = (int*)alloc(NEXP * 4);
  int* lists = (int*)alloc((size_t)NEXP * SEQ * 4);
  int* slotof = (int*)alloc((size_t)NEXP * SEQ * 4);
  unsigned short* gated = (unsigned short*)alloc((size_t)2 * SEQ * INTER * 2);
  float* scr = (float*)alloc((size_t)2 * SEQ * HD * 4);
  (void)ws_size;
  (void)off;

  rmsnorm_split_kernel<<<SEQ, 256, 0, stream>>>(x, ln1, xnh, xnl);
  // fused QKV: 96 n-blocks x 8 m-groups = 768 blocks (MT=2, BK=128)
  gemm_gl<2, 2, true, 0, 128><<<dim3(96, 8, 1), 256, 0, stream>>>(
      xnh, xnl, HD, Wq, Wk, Wv, bq, bk, bv, nullptr, nullptr, nullptr, nullptr,
      qbh, qbl, kbh, kbl, vth, vtl, nullptr, nullptr, SEQ, HD);
  attn_kernel<<<NHEAD * 64 / 4, 256, 0, stream>>>(qbh, qbl, kbh, kbl, vth, vtl,
                                                  sinks, ath, atl);
  // O-proj: 64 n-blocks x 8 m-groups = 512 blocks (MT=2, BK=128)
  gemm_gl<2, 2, true, 1, 128><<<dim3(64, 8, 1), 256, 0, stream>>>(
      ath, atl, NHEAD * DHEAD, Wo, nullptr, nullptr, bo, nullptr, nullptr, x,
      nullptr, nullptr, nullptr, nullptr, nullptr, nullptr, nullptr, nullptr,
      nullptr, hbuf, nullptr, SEQ, NHEAD * DHEAD);
  rmsnorm_plain_kernel<<<SEQ, 256, 0, stream>>>(hbuf, ln2, hn);
  hipMemsetAsync(counts, 0, NEXP * sizeof(int), stream);
  router_kernel<<<SEQ, 64, 0, stream>>>(hbuf, ln2, rw, rb, wsel, counts, lists,
                                        slotof);
  // FUSED gate+up+activation: 64 n-blocks x 8 experts (BK=128, 64KB LDS)
  gemm_gl<5, 2, false, 4, 128><<<dim3(64, 1, 8), 256, 0, stream>>>(
      hn, nullptr, HD, Wg, Wu, nullptr, bg, bu, nullptr, nullptr, counts, lists,
      slotof, nullptr, nullptr, nullptr, nullptr, nullptr, nullptr, nullptr,
      gated, SEQ, HD);
  // down: 64 n-blocks x 8 experts, f32 per slot (weights-once, BK=128)
  gemm_gl<5, 2, false, 3, 128><<<dim3(64, 1, 8), 256, 0, stream>>>(
      gated, nullptr, INTER, Wd, nullptr, nullptr, bd, nullptr, nullptr,
      nullptr, counts, slotof, slotof, nullptr, nullptr, nullptr, nullptr,
      nullptr, nullptr, scr, nullptr, SEQ, INTER);
  reduce_kernel<<<SEQ, 256, 0, stream>>>(hbuf, scr, wsel, out);
}